// Round 1
// baseline (3125.775 us; speedup 1.0000x reference)
//
#include <hip/hip_runtime.h>

#define NN 50000
#define NE 800000
#define D  96

// T1 = -H (scatter then adds 2*val*H[col] -> T1 = 2*spmm(H) - H)
__global__ void init_t1(const float4* __restrict__ H, float4* __restrict__ T1, int n4) {
    int i = blockIdx.x * blockDim.x + threadIdx.x;
    if (i < n4) {
        float4 h = H[i];
        T1[i] = make_float4(-h.x, -h.y, -h.z, -h.w);
    }
}

// Tn = -2*Tc - Tp (scatter then adds 4*val*Tc[col] -> Tn = 4*spmm(Tc) - 2*Tc - Tp)
__global__ void init_next(const float4* __restrict__ Tc, const float4* __restrict__ Tp,
                          float4* __restrict__ Tn, int n4) {
    int i = blockIdx.x * blockDim.x + threadIdx.x;
    if (i < n4) {
        float4 c = Tc[i];
        float4 p = Tp[i];
        Tn[i] = make_float4(-2.0f * c.x - p.x, -2.0f * c.y - p.y,
                            -2.0f * c.z - p.z, -2.0f * c.w - p.w);
    }
}

// Edge scatter: Y[rows[e]] += scale * vals[e] * X[cols[e]]
// 24 threads per edge, each handling one float4 (4 features).
__global__ void scatter(const int* __restrict__ rows, const int* __restrict__ cols,
                        const float* __restrict__ vals, const float* __restrict__ X,
                        float* __restrict__ Y, float scale, int total) {
    int tid = blockIdx.x * blockDim.x + threadIdx.x;
    if (tid >= total) return;
    int e = tid / 24;
    int q = tid - e * 24;
    int row = rows[e];
    int col = cols[e];
    float v = vals[e] * scale;
    const float4* xp = (const float4*)(X + (size_t)col * D);
    float4 x = xp[q];
    float* yp = Y + (size_t)row * D + q * 4;
    atomicAdd(yp + 0, v * x.x);
    atomicAdd(yp + 1, v * x.y);
    atomicAdd(yp + 2, v * x.z);
    atomicAdd(yp + 3, v * x.w);
}

// out[r] = (H[r]+T1[r]+T2[r]+T3[r]) @ W + bias
// Block = 256 threads = 8 groups of 32 lanes; each group handles one row at a
// time (grid-stride). W (96x96) staged in LDS once per block.
__global__ void cheb_gemm(const float* __restrict__ H, const float* __restrict__ T1,
                          const float* __restrict__ T2, const float* __restrict__ T3,
                          const float* __restrict__ W, const float* __restrict__ bias,
                          float* __restrict__ out, int n_nodes) {
    __shared__ float Wl[D * D];     // 36.9 KB
    __shared__ float bl[D];
    __shared__ float Srow[8 * D];   // per-group summed row

    int tid = threadIdx.x;
    for (int i = tid; i < D * D; i += 256) Wl[i] = W[i];
    if (tid < D) bl[tid] = bias[tid];
    __syncthreads();

    int lane  = tid & 31;
    int group = tid >> 5;           // 0..7
    float* srow = Srow + group * D;

    for (int r = blockIdx.x * 8 + group; r < n_nodes; r += gridDim.x * 8) {
        const float* h  = H  + (size_t)r * D;
        const float* t1 = T1 + (size_t)r * D;
        const float* t2 = T2 + (size_t)r * D;
        const float* t3 = T3 + (size_t)r * D;
        // Cooperative (within half-wave group, lockstep, no barrier needed)
        // load+sum of the row into LDS.
        for (int k = lane; k < D; k += 32)
            srow[k] = h[k] + t1[k] + t2[k] + t3[k];

        float acc0 = bl[lane];
        float acc1 = bl[lane + 32];
        float acc2 = bl[lane + 64];
        #pragma unroll 8
        for (int k = 0; k < D; ++k) {
            float s = srow[k];      // LDS broadcast, conflict-free
            acc0 += s * Wl[k * D + lane];
            acc1 += s * Wl[k * D + lane + 32];
            acc2 += s * Wl[k * D + lane + 64];
        }
        float* o = out + (size_t)r * D;
        o[lane]      = acc0;
        o[lane + 32] = acc1;
        o[lane + 64] = acc2;
    }
}

extern "C" void kernel_launch(void* const* d_in, const int* in_sizes, int n_in,
                              void* d_out, int out_size, void* d_ws, size_t ws_size,
                              hipStream_t stream) {
    const int*   rows = (const int*)d_in[0];
    const int*   cols = (const int*)d_in[1];
    const float* vals = (const float*)d_in[2];
    const float* H    = (const float*)d_in[3];
    const float* W    = (const float*)d_in[4];
    const float* bias = (const float*)d_in[5];
    float* out = (float*)d_out;

    float* T1 = (float*)d_ws;
    float* T2 = T1 + (size_t)NN * D;
    float* T3 = T2 + (size_t)NN * D;

    const int n4 = NN * D / 4;                 // 1.2M float4s
    const int eb = (n4 + 255) / 256;
    const int total = NE * 24;                 // 19.2M scatter threads
    const int sb = (total + 255) / 256;

    // T1 = 2*spmm(H) - H
    init_t1<<<eb, 256, 0, stream>>>((const float4*)H, (float4*)T1, n4);
    scatter<<<sb, 256, 0, stream>>>(rows, cols, vals, H, T1, 2.0f, total);
    // T2 = 4*spmm(T1) - 2*T1 - H
    init_next<<<eb, 256, 0, stream>>>((const float4*)T1, (const float4*)H, (float4*)T2, n4);
    scatter<<<sb, 256, 0, stream>>>(rows, cols, vals, T1, T2, 4.0f, total);
    // T3 = 4*spmm(T2) - 2*T2 - T1
    init_next<<<eb, 256, 0, stream>>>((const float4*)T2, (const float4*)T1, (float4*)T3, n4);
    scatter<<<sb, 256, 0, stream>>>(rows, cols, vals, T2, T3, 4.0f, total);
    // out = (H + T1 + T2 + T3) @ W + bias
    cheb_gemm<<<2048, 256, 0, stream>>>(H, T1, T2, T3, W, bias, out, NN);
}

// Round 2
// 438.590 us; speedup vs baseline: 7.1269x; 7.1269x over previous
//
#include <hip/hip_runtime.h>

#define NN 50000
#define NE 800000
#define D  96

// ---------------- CSR build (every launch; ws is re-poisoned) ----------------

__global__ void zero_counts(int* __restrict__ counts) {
    int i = blockIdx.x * blockDim.x + threadIdx.x;
    if (i < NN) counts[i] = 0;
}

// slot[e] = running index of edge e within its row
__global__ void hist_slots(const int* __restrict__ rows, int* __restrict__ counts,
                           int* __restrict__ slot) {
    int e = blockIdx.x * blockDim.x + threadIdx.x;
    if (e < NE) slot[e] = atomicAdd(&counts[rows[e]], 1);
}

// Single-block exclusive scan of counts[NN] -> row_ptr[NN+1]
__global__ void scan_counts(const int* __restrict__ counts, int* __restrict__ row_ptr) {
    __shared__ int part[1024];
    const int CHUNK = (NN + 1023) / 1024;   // 49
    int t = threadIdx.x;
    int base = t * CHUNK;
    int s = 0;
    for (int i = 0; i < CHUNK; ++i) {
        int idx = base + i;
        if (idx < NN) s += counts[idx];
    }
    part[t] = s;
    __syncthreads();
    // Hillis-Steele inclusive scan
    for (int off = 1; off < 1024; off <<= 1) {
        int v = (t >= off) ? part[t - off] : 0;
        __syncthreads();
        part[t] += v;
        __syncthreads();
    }
    int excl = (t == 0) ? 0 : part[t - 1];
    for (int i = 0; i < CHUNK; ++i) {
        int idx = base + i;
        if (idx < NN) {
            row_ptr[idx] = excl;
            excl += counts[idx];
        }
    }
    if (t == 1023) row_ptr[NN] = excl;      // == NE
}

// edges[row_ptr[rows[e]] + slot[e]] = (col, val)
__global__ void fill_edges(const int* __restrict__ rows, const int* __restrict__ cols,
                           const float* __restrict__ vals, const int* __restrict__ row_ptr,
                           const int* __restrict__ slot, int2* __restrict__ edges) {
    int e = blockIdx.x * blockDim.x + threadIdx.x;
    if (e < NE) {
        int p = row_ptr[rows[e]] + slot[e];
        edges[p] = make_int2(cols[e], __float_as_int(vals[e]));
    }
}

// ---------------- SpMM: Y[r] = ca*A[r] + cb*B[r] + scale * sum val*X[col] ----
// 32 lanes per row (lane owns features f, f+32, f+64); 8 rows per 256-block.
__global__ void spmm(const int* __restrict__ row_ptr, const int2* __restrict__ edges,
                     const float* __restrict__ X, const float* __restrict__ A,
                     const float* __restrict__ B, float* __restrict__ Y,
                     float scale, float ca, float cb, int n_nodes) {
    int tid  = threadIdx.x;
    int lane = tid & 31;
    int g    = tid >> 5;
    for (int r = blockIdx.x * 8 + g; r < n_nodes; r += gridDim.x * 8) {
        const float* a = A + (size_t)r * D;
        const float* b = B + (size_t)r * D;
        float acc0 = ca * a[lane]      + cb * b[lane];
        float acc1 = ca * a[lane + 32] + cb * b[lane + 32];
        float acc2 = ca * a[lane + 64] + cb * b[lane + 64];
        int s = row_ptr[r];
        int e = row_ptr[r + 1];
        for (int i = s; i < e; ++i) {
            int2 ed = edges[i];                 // broadcast (same addr all lanes)
            float v = scale * __int_as_float(ed.y);
            const float* x = X + (size_t)ed.x * D;
            acc0 += v * x[lane];
            acc1 += v * x[lane + 32];
            acc2 += v * x[lane + 64];
        }
        float* y = Y + (size_t)r * D;
        y[lane]      = acc0;
        y[lane + 32] = acc1;
        y[lane + 64] = acc2;
    }
}

// ---------------- out[r] = (H+T1+T2+T3)[r] @ W + bias ------------------------
__global__ void cheb_gemm(const float* __restrict__ H, const float* __restrict__ T1,
                          const float* __restrict__ T2, const float* __restrict__ T3,
                          const float* __restrict__ W, const float* __restrict__ bias,
                          float* __restrict__ out, int n_nodes) {
    __shared__ float Wl[D * D];
    __shared__ float bl[D];
    __shared__ float Srow[8 * D];

    int tid = threadIdx.x;
    for (int i = tid; i < D * D; i += 256) Wl[i] = W[i];
    if (tid < D) bl[tid] = bias[tid];
    __syncthreads();

    int lane  = tid & 31;
    int group = tid >> 5;
    float* srow = Srow + group * D;

    for (int r = blockIdx.x * 8 + group; r < n_nodes; r += gridDim.x * 8) {
        const float* h  = H  + (size_t)r * D;
        const float* t1 = T1 + (size_t)r * D;
        const float* t2 = T2 + (size_t)r * D;
        const float* t3 = T3 + (size_t)r * D;
        for (int k = lane; k < D; k += 32)
            srow[k] = h[k] + t1[k] + t2[k] + t3[k];

        float acc0 = bl[lane];
        float acc1 = bl[lane + 32];
        float acc2 = bl[lane + 64];
        #pragma unroll 8
        for (int k = 0; k < D; ++k) {
            float s = srow[k];
            acc0 += s * Wl[k * D + lane];
            acc1 += s * Wl[k * D + lane + 32];
            acc2 += s * Wl[k * D + lane + 64];
        }
        float* o = out + (size_t)r * D;
        o[lane]      = acc0;
        o[lane + 32] = acc1;
        o[lane + 64] = acc2;
    }
}

extern "C" void kernel_launch(void* const* d_in, const int* in_sizes, int n_in,
                              void* d_out, int out_size, void* d_ws, size_t ws_size,
                              hipStream_t stream) {
    const int*   rows = (const int*)d_in[0];
    const int*   cols = (const int*)d_in[1];
    const float* vals = (const float*)d_in[2];
    const float* H    = (const float*)d_in[3];
    const float* W    = (const float*)d_in[4];
    const float* bias = (const float*)d_in[5];
    float* out = (float*)d_out;

    // Workspace layout (all offsets 8B-aligned):
    char* ws = (char*)d_ws;
    float* T1      = (float*)ws;                       ws += (size_t)NN * D * 4;  // 19.2 MB
    float* T2      = (float*)ws;                       ws += (size_t)NN * D * 4;
    float* T3      = (float*)ws;                       ws += (size_t)NN * D * 4;
    int2*  edges   = (int2*)ws;                        ws += (size_t)NE * 8;      // 6.4 MB
    int*   counts  = (int*)ws;                         ws += (size_t)NN * 4;
    int*   row_ptr = (int*)ws;                         ws += (size_t)(NN + 1) * 4;
    int*   slot    = (int*)ws;                         /* NE * 4 */

    const int nb = (NN + 255) / 256;
    const int eb = (NE + 255) / 256;

    // CSR build
    zero_counts<<<nb, 256, 0, stream>>>(counts);
    hist_slots<<<eb, 256, 0, stream>>>(rows, counts, slot);
    scan_counts<<<1, 1024, 0, stream>>>(counts, row_ptr);
    fill_edges<<<eb, 256, 0, stream>>>(rows, cols, vals, row_ptr, slot, edges);

    const int sb = (NN + 7) / 8;   // 6250 blocks, 8 rows/block

    // T1 = 2*spmm(H) - H
    spmm<<<sb, 256, 0, stream>>>(row_ptr, edges, H, H, H, T1, 2.0f, -1.0f, 0.0f, NN);
    // T2 = 4*spmm(T1) - 2*T1 - H
    spmm<<<sb, 256, 0, stream>>>(row_ptr, edges, T1, T1, H, T2, 4.0f, -2.0f, -1.0f, NN);
    // T3 = 4*spmm(T2) - 2*T2 - T1
    spmm<<<sb, 256, 0, stream>>>(row_ptr, edges, T2, T2, T1, T3, 4.0f, -2.0f, -1.0f, NN);
    // out = (H + T1 + T2 + T3) @ W + bias
    cheb_gemm<<<2048, 256, 0, stream>>>(H, T1, T2, T3, W, bias, out, NN);
}

// Round 3
// 335.163 us; speedup vs baseline: 9.3261x; 1.3086x over previous
//
#include <hip/hip_runtime.h>

#define NN 50000
#define NE 800000
#define D  96
#define NB_SCAN 196   // ceil(NN/256)

// ---------------- CSR build ----------------

__global__ void zero_counts(int* __restrict__ counts) {
    int i = blockIdx.x * blockDim.x + threadIdx.x;
    if (i < NN) counts[i] = 0;
}

__global__ void hist_slots(const int* __restrict__ rows, int* __restrict__ counts,
                           int* __restrict__ slot) {
    int e = blockIdx.x * blockDim.x + threadIdx.x;
    if (e < NE) slot[e] = atomicAdd(&counts[rows[e]], 1);
}

// partials[b] = sum of counts in block b's 256-chunk
__global__ void scan_p1(const int* __restrict__ counts, int* __restrict__ partials) {
    __shared__ int red[256];
    int t = threadIdx.x;
    int i = blockIdx.x * 256 + t;
    red[t] = (i < NN) ? counts[i] : 0;
    __syncthreads();
    for (int off = 128; off > 0; off >>= 1) {
        if (t < off) red[t] += red[t + off];
        __syncthreads();
    }
    if (t == 0) partials[blockIdx.x] = red[0];
}

// in-place exclusive scan of partials[NB_SCAN] (single small block)
__global__ void scan_p2(int* __restrict__ partials) {
    __shared__ int sh[256];
    int t = threadIdx.x;
    int v = (t < NB_SCAN) ? partials[t] : 0;
    sh[t] = v;
    __syncthreads();
    for (int off = 1; off < 256; off <<= 1) {
        int u = (t >= off) ? sh[t - off] : 0;
        __syncthreads();
        sh[t] += u;
        __syncthreads();
    }
    if (t < NB_SCAN) partials[t] = sh[t] - v;   // exclusive
}

// row_ptr[i] = partials[block] + local exclusive scan
__global__ void scan_p3(const int* __restrict__ counts, const int* __restrict__ partials,
                        int* __restrict__ row_ptr) {
    __shared__ int sh[256];
    int t = threadIdx.x;
    int i = blockIdx.x * 256 + t;
    int v = (i < NN) ? counts[i] : 0;
    sh[t] = v;
    __syncthreads();
    for (int off = 1; off < 256; off <<= 1) {
        int u = (t >= off) ? sh[t - off] : 0;
        __syncthreads();
        sh[t] += u;
        __syncthreads();
    }
    int excl = sh[t] - v + partials[blockIdx.x];
    if (i < NN) row_ptr[i] = excl;
    if (i == NN - 1) row_ptr[NN] = excl + v;    // == NE
}

__global__ void fill_edges(const int* __restrict__ rows, const int* __restrict__ cols,
                           const float* __restrict__ vals, const int* __restrict__ row_ptr,
                           const int* __restrict__ slot, int2* __restrict__ edges) {
    int e = blockIdx.x * blockDim.x + threadIdx.x;
    if (e < NE) {
        int p = row_ptr[rows[e]] + slot[e];
        edges[p] = make_int2(cols[e], __float_as_int(vals[e]));
    }
}

// ---------------- SpMM: Y[r] = ca*A[r] + cb*B[r] + scale * sum val*X[col] ----
// 32 lanes per row; lanes 0..23 each own one float4 (4 features). One
// global_load_dwordx4 per edge per group, unrolled x2 for MLP.
__global__ void spmm(const int* __restrict__ row_ptr, const int2* __restrict__ edges,
                     const float* __restrict__ X, const float* __restrict__ A,
                     const float* __restrict__ B, float* __restrict__ Y,
                     float scale, float ca, float cb, int n_nodes) {
    int tid  = threadIdx.x;
    int lane = tid & 31;
    int g    = tid >> 5;
    int r = blockIdx.x * 8 + g;
    if (r >= n_nodes) return;
    bool act = lane < 24;

    float4 acc = make_float4(0.f, 0.f, 0.f, 0.f);
    if (act) {
        float4 av = ((const float4*)(A + (size_t)r * D))[lane];
        float4 bv = ((const float4*)(B + (size_t)r * D))[lane];
        acc.x = ca * av.x + cb * bv.x;
        acc.y = ca * av.y + cb * bv.y;
        acc.z = ca * av.z + cb * bv.z;
        acc.w = ca * av.w + cb * bv.w;
    }

    int s = row_ptr[r];
    int e = row_ptr[r + 1];
    int i = s;
    for (; i + 1 < e; i += 2) {
        int2 e0 = edges[i];
        int2 e1 = edges[i + 1];
        float4 x0 = make_float4(0.f, 0.f, 0.f, 0.f);
        float4 x1 = make_float4(0.f, 0.f, 0.f, 0.f);
        if (act) {
            x0 = ((const float4*)(X + (size_t)e0.x * D))[lane];
            x1 = ((const float4*)(X + (size_t)e1.x * D))[lane];
        }
        float v0 = scale * __int_as_float(e0.y);
        float v1 = scale * __int_as_float(e1.y);
        acc.x += v0 * x0.x + v1 * x1.x;
        acc.y += v0 * x0.y + v1 * x1.y;
        acc.z += v0 * x0.z + v1 * x1.z;
        acc.w += v0 * x0.w + v1 * x1.w;
    }
    if (i < e) {
        int2 e0 = edges[i];
        float v0 = scale * __int_as_float(e0.y);
        if (act) {
            float4 x0 = ((const float4*)(X + (size_t)e0.x * D))[lane];
            acc.x += v0 * x0.x;
            acc.y += v0 * x0.y;
            acc.z += v0 * x0.z;
            acc.w += v0 * x0.w;
        }
    }
    if (act) ((float4*)(Y + (size_t)r * D))[lane] = acc;
}

// ---------------- out[r] = S[r] @ W + bias ------------------------
__global__ void cheb_gemm(const float* __restrict__ S, const float* __restrict__ W,
                          const float* __restrict__ bias, float* __restrict__ out,
                          int n_nodes) {
    __shared__ float Wl[D * D];
    __shared__ float bl[D];
    __shared__ float Srow[8 * D];

    int tid = threadIdx.x;
    for (int i = tid; i < D * D; i += 256) Wl[i] = W[i];
    if (tid < D) bl[tid] = bias[tid];
    __syncthreads();

    int lane  = tid & 31;
    int group = tid >> 5;
    float* srow = Srow + group * D;

    for (int r = blockIdx.x * 8 + group; r < n_nodes; r += gridDim.x * 8) {
        const float* s = S + (size_t)r * D;
        for (int k = lane; k < D; k += 32) srow[k] = s[k];

        float acc0 = bl[lane];
        float acc1 = bl[lane + 32];
        float acc2 = bl[lane + 64];
        #pragma unroll 8
        for (int k = 0; k < D; ++k) {
            float sv = srow[k];
            acc0 += sv * Wl[k * D + lane];
            acc1 += sv * Wl[k * D + lane + 32];
            acc2 += sv * Wl[k * D + lane + 64];
        }
        float* o = out + (size_t)r * D;
        o[lane]      = acc0;
        o[lane + 32] = acc1;
        o[lane + 64] = acc2;
    }
}

extern "C" void kernel_launch(void* const* d_in, const int* in_sizes, int n_in,
                              void* d_out, int out_size, void* d_ws, size_t ws_size,
                              hipStream_t stream) {
    const int*   rows = (const int*)d_in[0];
    const int*   cols = (const int*)d_in[1];
    const float* vals = (const float*)d_in[2];
    const float* H    = (const float*)d_in[3];
    const float* W    = (const float*)d_in[4];
    const float* bias = (const float*)d_in[5];
    float* out = (float*)d_out;

    char* ws = (char*)d_ws;
    float* T1       = (float*)ws;   ws += (size_t)NN * D * 4;   // 19.2 MB
    float* T2       = (float*)ws;   ws += (size_t)NN * D * 4;
    float* S        = (float*)ws;   ws += (size_t)NN * D * 4;   // S = H+T1+T2+T3
    int2*  edges    = (int2*)ws;    ws += (size_t)NE * 8;       // 6.4 MB
    int*   counts   = (int*)ws;     ws += (size_t)NN * 4;
    int*   row_ptr  = (int*)ws;     ws += (size_t)(NN + 1) * 4;
    int*   partials = (int*)ws;     ws += 256 * 4;
    int*   slot     = (int*)ws;     /* NE * 4 */

    const int nb = (NN + 255) / 256;   // 196
    const int eb = (NE + 255) / 256;

    // CSR build
    zero_counts<<<nb, 256, 0, stream>>>(counts);
    hist_slots<<<eb, 256, 0, stream>>>(rows, counts, slot);
    scan_p1<<<NB_SCAN, 256, 0, stream>>>(counts, partials);
    scan_p2<<<1, 256, 0, stream>>>(partials);
    scan_p3<<<NB_SCAN, 256, 0, stream>>>(counts, partials, row_ptr);
    fill_edges<<<eb, 256, 0, stream>>>(rows, cols, vals, row_ptr, slot, edges);

    const int sb = (NN + 7) / 8;   // 6250 blocks, 8 rows/block

    // T1 = 2*spmm(H) - H
    spmm<<<sb, 256, 0, stream>>>(row_ptr, edges, H, H, H, T1, 2.0f, -1.0f, 0.0f, NN);
    // T2 = 4*spmm(T1) - 2*T1 - H
    spmm<<<sb, 256, 0, stream>>>(row_ptr, edges, T1, T1, H, T2, 4.0f, -2.0f, -1.0f, NN);
    // S  = H + T1 + T2 + T3 = 4*spmm(T2) + H - T2   (T1 cancels)
    spmm<<<sb, 256, 0, stream>>>(row_ptr, edges, T2, H, T2, S, 4.0f, 1.0f, -1.0f, NN);
    // out = S @ W + bias
    cheb_gemm<<<2048, 256, 0, stream>>>(S, W, bias, out, NN);
}

// Round 4
// 293.159 us; speedup vs baseline: 10.6624x; 1.1433x over previous
//
#include <hip/hip_runtime.h>
#include <hip/hip_fp16.h>

#define NN 50000
#define NE 800000
#define D  96
#define NB_SCAN 196   // ceil(NN/256)

typedef unsigned int  uint32;
typedef unsigned short uint16;

__device__ inline uint16 f32_to_bf16(float f) {          // round-nearest-even
    uint32 u = __float_as_uint(f);
    u += 0x7FFF + ((u >> 16) & 1);
    return (uint16)(u >> 16);
}
__device__ inline float bf16_to_f32(uint16 h) {
    return __uint_as_float(((uint32)h) << 16);
}

// ---------------- H -> bf16 copy ----------------
__global__ void to_bf16(const float4* __restrict__ X, ushort4* __restrict__ Xb, int n4) {
    int i = blockIdx.x * blockDim.x + threadIdx.x;
    if (i < n4) {
        float4 v = X[i];
        ushort4 o;
        o.x = f32_to_bf16(v.x); o.y = f32_to_bf16(v.y);
        o.z = f32_to_bf16(v.z); o.w = f32_to_bf16(v.w);
        Xb[i] = o;
    }
}

// ---------------- CSR build ----------------
__global__ void zero_counts(int* __restrict__ counts) {
    int i = blockIdx.x * blockDim.x + threadIdx.x;
    if (i < NN) counts[i] = 0;
}

__global__ void hist_slots(const int* __restrict__ rows, int* __restrict__ counts,
                           int* __restrict__ slot) {
    int e = blockIdx.x * blockDim.x + threadIdx.x;
    if (e < NE) slot[e] = atomicAdd(&counts[rows[e]], 1);
}

__global__ void scan_p1(const int* __restrict__ counts, int* __restrict__ partials) {
    __shared__ int red[256];
    int t = threadIdx.x;
    int i = blockIdx.x * 256 + t;
    red[t] = (i < NN) ? counts[i] : 0;
    __syncthreads();
    for (int off = 128; off > 0; off >>= 1) {
        if (t < off) red[t] += red[t + off];
        __syncthreads();
    }
    if (t == 0) partials[blockIdx.x] = red[0];
}

__global__ void scan_p2(int* __restrict__ partials) {
    __shared__ int sh[256];
    int t = threadIdx.x;
    int v = (t < NB_SCAN) ? partials[t] : 0;
    sh[t] = v;
    __syncthreads();
    for (int off = 1; off < 256; off <<= 1) {
        int u = (t >= off) ? sh[t - off] : 0;
        __syncthreads();
        sh[t] += u;
        __syncthreads();
    }
    if (t < NB_SCAN) partials[t] = sh[t] - v;
}

__global__ void scan_p3(const int* __restrict__ counts, const int* __restrict__ partials,
                        int* __restrict__ row_ptr) {
    __shared__ int sh[256];
    int t = threadIdx.x;
    int i = blockIdx.x * 256 + t;
    int v = (i < NN) ? counts[i] : 0;
    sh[t] = v;
    __syncthreads();
    for (int off = 1; off < 256; off <<= 1) {
        int u = (t >= off) ? sh[t - off] : 0;
        __syncthreads();
        sh[t] += u;
        __syncthreads();
    }
    int excl = sh[t] - v + partials[blockIdx.x];
    if (i < NN) row_ptr[i] = excl;
    if (i == NN - 1) row_ptr[NN] = excl + v;
}

// edge = col (low 16) | f16(val) (high 16)
__global__ void fill_edges(const int* __restrict__ rows, const int* __restrict__ cols,
                           const float* __restrict__ vals, const int* __restrict__ row_ptr,
                           const int* __restrict__ slot, uint32* __restrict__ edges) {
    int e = blockIdx.x * blockDim.x + threadIdx.x;
    if (e < NE) {
        int p = row_ptr[rows[e]] + slot[e];
        __half_raw hr = __half_raw(__float2half(vals[e]));
        edges[p] = (uint32)(cols[e] & 0xFFFF) | ((uint32)hr.x << 16);
    }
}

// -------- SpMM: Y = ca*A + cb*B + scale * sum val * Xb[col]  (Xb bf16) ------
// 32 lanes per row; lanes 0..23 own 4 feats each (ushort4 gather = 8 B).
// Also emits bf16 copy Yb (for the next pass's gather) unless null.
__global__ void spmm(const int* __restrict__ row_ptr, const uint32* __restrict__ edges,
                     const uint16* __restrict__ Xb, const float* __restrict__ A,
                     const float* __restrict__ B, float* __restrict__ Y,
                     uint16* __restrict__ Yb,
                     float scale, float ca, float cb, int n_nodes) {
    int tid  = threadIdx.x;
    int lane = tid & 31;
    int g    = tid >> 5;
    int r = blockIdx.x * 8 + g;
    if (r >= n_nodes) return;
    bool act = lane < 24;

    float4 acc = make_float4(0.f, 0.f, 0.f, 0.f);
    if (act) {
        float4 av = ((const float4*)(A + (size_t)r * D))[lane];
        float4 bv = ((const float4*)(B + (size_t)r * D))[lane];
        acc.x = ca * av.x + cb * bv.x;
        acc.y = ca * av.y + cb * bv.y;
        acc.z = ca * av.z + cb * bv.z;
        acc.w = ca * av.w + cb * bv.w;
    }

    int s = row_ptr[r];
    int e = row_ptr[r + 1];
    int i = s;
    for (; i + 3 < e; i += 4) {
        uint32 e0 = edges[i], e1 = edges[i+1], e2 = edges[i+2], e3 = edges[i+3];
        ushort4 x0, x1, x2, x3;
        x0.x=x0.y=x0.z=x0.w=0; x1=x0; x2=x0; x3=x0;
        if (act) {
            x0 = ((const ushort4*)(Xb + (size_t)(e0 & 0xFFFF) * D))[lane];
            x1 = ((const ushort4*)(Xb + (size_t)(e1 & 0xFFFF) * D))[lane];
            x2 = ((const ushort4*)(Xb + (size_t)(e2 & 0xFFFF) * D))[lane];
            x3 = ((const ushort4*)(Xb + (size_t)(e3 & 0xFFFF) * D))[lane];
        }
        __half_raw h0, h1, h2, h3;
        h0.x = (uint16)(e0 >> 16); h1.x = (uint16)(e1 >> 16);
        h2.x = (uint16)(e2 >> 16); h3.x = (uint16)(e3 >> 16);
        float v0 = scale * __half2float(__half(h0));
        float v1 = scale * __half2float(__half(h1));
        float v2 = scale * __half2float(__half(h2));
        float v3 = scale * __half2float(__half(h3));
        acc.x += v0*bf16_to_f32(x0.x) + v1*bf16_to_f32(x1.x) + v2*bf16_to_f32(x2.x) + v3*bf16_to_f32(x3.x);
        acc.y += v0*bf16_to_f32(x0.y) + v1*bf16_to_f32(x1.y) + v2*bf16_to_f32(x2.y) + v3*bf16_to_f32(x3.y);
        acc.z += v0*bf16_to_f32(x0.z) + v1*bf16_to_f32(x1.z) + v2*bf16_to_f32(x2.z) + v3*bf16_to_f32(x3.z);
        acc.w += v0*bf16_to_f32(x0.w) + v1*bf16_to_f32(x1.w) + v2*bf16_to_f32(x2.w) + v3*bf16_to_f32(x3.w);
    }
    for (; i < e; ++i) {
        uint32 e0 = edges[i];
        __half_raw h0; h0.x = (uint16)(e0 >> 16);
        float v0 = scale * __half2float(__half(h0));
        if (act) {
            ushort4 x0 = ((const ushort4*)(Xb + (size_t)(e0 & 0xFFFF) * D))[lane];
            acc.x += v0 * bf16_to_f32(x0.x);
            acc.y += v0 * bf16_to_f32(x0.y);
            acc.z += v0 * bf16_to_f32(x0.z);
            acc.w += v0 * bf16_to_f32(x0.w);
        }
    }
    if (act) {
        ((float4*)(Y + (size_t)r * D))[lane] = acc;
        if (Yb) {
            ushort4 ob;
            ob.x = f32_to_bf16(acc.x); ob.y = f32_to_bf16(acc.y);
            ob.z = f32_to_bf16(acc.z); ob.w = f32_to_bf16(acc.w);
            ((ushort4*)(Yb + (size_t)r * D))[lane] = ob;
        }
    }
}

// ---------------- out[r] = S[r] @ W + bias ------------------------
__global__ void cheb_gemm(const float* __restrict__ S, const float* __restrict__ W,
                          const float* __restrict__ bias, float* __restrict__ out,
                          int n_nodes) {
    __shared__ float Wl[D * D];
    __shared__ float bl[D];
    __shared__ float Srow[8 * D];

    int tid = threadIdx.x;
    for (int i = tid; i < D * D; i += 256) Wl[i] = W[i];
    if (tid < D) bl[tid] = bias[tid];
    __syncthreads();

    int lane  = tid & 31;
    int group = tid >> 5;
    float* srow = Srow + group * D;

    for (int r = blockIdx.x * 8 + group; r < n_nodes; r += gridDim.x * 8) {
        const float* s = S + (size_t)r * D;
        for (int k = lane; k < D; k += 32) srow[k] = s[k];

        float acc0 = bl[lane];
        float acc1 = bl[lane + 32];
        float acc2 = bl[lane + 64];
        #pragma unroll 8
        for (int k = 0; k < D; ++k) {
            float sv = srow[k];
            acc0 += sv * Wl[k * D + lane];
            acc1 += sv * Wl[k * D + lane + 32];
            acc2 += sv * Wl[k * D + lane + 64];
        }
        float* o = out + (size_t)r * D;
        o[lane]      = acc0;
        o[lane + 32] = acc1;
        o[lane + 64] = acc2;
    }
}

extern "C" void kernel_launch(void* const* d_in, const int* in_sizes, int n_in,
                              void* d_out, int out_size, void* d_ws, size_t ws_size,
                              hipStream_t stream) {
    const int*   rows = (const int*)d_in[0];
    const int*   cols = (const int*)d_in[1];
    const float* vals = (const float*)d_in[2];
    const float* H    = (const float*)d_in[3];
    const float* W    = (const float*)d_in[4];
    const float* bias = (const float*)d_in[5];
    float* out = (float*)d_out;

    // Workspace (aliasing: buf0 serves as slot -> T1 -> S over time)
    char* ws = (char*)d_ws;
    float*  buf0     = (float*)ws;   ws += (size_t)NN * D * 4;   // 19.2 MB
    float*  T2       = (float*)ws;   ws += (size_t)NN * D * 4;   // 19.2 MB
    uint16* Hb       = (uint16*)ws;  ws += (size_t)NN * D * 2;   // 9.6 MB
    uint16* T1b      = (uint16*)ws;  ws += (size_t)NN * D * 2;
    uint16* T2b      = (uint16*)ws;  ws += (size_t)NN * D * 2;
    uint32* edges    = (uint32*)ws;  ws += (size_t)NE * 4;       // 3.2 MB
    int*    counts   = (int*)ws;     ws += (size_t)NN * 4;
    int*    row_ptr  = (int*)ws;     ws += (size_t)(NN + 1) * 4;
    int*    partials = (int*)ws;     ws += 256 * 4;
    int*    slot     = (int*)buf0;   // dead before first spmm writes buf0
    float*  T1       = buf0;
    float*  S        = buf0;         // pass 3 reads only H, T2, T2b

    const int nb = (NN + 255) / 256;
    const int eb = (NE + 255) / 256;
    const int n4 = NN * D / 4;
    const int cb4 = (n4 + 255) / 256;

    to_bf16<<<cb4, 256, 0, stream>>>((const float4*)H, (ushort4*)Hb, n4);

    zero_counts<<<nb, 256, 0, stream>>>(counts);
    hist_slots<<<eb, 256, 0, stream>>>(rows, counts, slot);
    scan_p1<<<NB_SCAN, 256, 0, stream>>>(counts, partials);
    scan_p2<<<1, 256, 0, stream>>>(partials);
    scan_p3<<<NB_SCAN, 256, 0, stream>>>(counts, partials, row_ptr);
    fill_edges<<<eb, 256, 0, stream>>>(rows, cols, vals, row_ptr, slot, edges);

    const int sb = (NN + 7) / 8;

    // T1 = 2*spmm(H) - H
    spmm<<<sb, 256, 0, stream>>>(row_ptr, edges, Hb, H, H, T1, T1b, 2.0f, -1.0f, 0.0f, NN);
    // T2 = 4*spmm(T1) - 2*T1 - H
    spmm<<<sb, 256, 0, stream>>>(row_ptr, edges, T1b, T1, H, T2, T2b, 4.0f, -2.0f, -1.0f, NN);
    // S = H + T1 + T2 + T3 = 4*spmm(T2) + H - T2
    spmm<<<sb, 256, 0, stream>>>(row_ptr, edges, T2b, H, T2, S, (uint16*)nullptr, 4.0f, 1.0f, -1.0f, NN);
    // out = S @ W + bias
    cheb_gemm<<<2048, 256, 0, stream>>>(S, W, bias, out, NN);
}

// Round 5
// 258.489 us; speedup vs baseline: 12.0925x; 1.1341x over previous
//
#include <hip/hip_runtime.h>
#include <hip/hip_fp16.h>

#define NN 50000
#define NE 800000
#define D  96
#define NB_SCAN 196   // ceil(NN/256)

typedef unsigned int   uint32;
typedef unsigned short uint16;
typedef short v8s __attribute__((ext_vector_type(8)));   // 8 bf16 (4 VGPRs)
typedef float v4f __attribute__((ext_vector_type(4)));   // MFMA accumulator

__device__ inline uint16 f32_to_bf16(float f) {          // round-nearest-even
    uint32 u = __float_as_uint(f);
    u += 0x7FFF + ((u >> 16) & 1);
    return (uint16)(u >> 16);
}
__device__ inline float bf16_to_f32(uint16 h) {
    return __uint_as_float(((uint32)h) << 16);
}

// ---------------- H -> bf16 copy ----------------
__global__ void to_bf16(const float4* __restrict__ X, ushort4* __restrict__ Xb, int n4) {
    int i = blockIdx.x * blockDim.x + threadIdx.x;
    if (i < n4) {
        float4 v = X[i];
        ushort4 o;
        o.x = f32_to_bf16(v.x); o.y = f32_to_bf16(v.y);
        o.z = f32_to_bf16(v.z); o.w = f32_to_bf16(v.w);
        Xb[i] = o;
    }
}

// ---------------- CSR build ----------------
__global__ void zero_counts(int* __restrict__ counts) {
    int i = blockIdx.x * blockDim.x + threadIdx.x;
    if (i < NN) counts[i] = 0;
}

__global__ void hist_slots(const int* __restrict__ rows, int* __restrict__ counts,
                           int* __restrict__ slot) {
    int e = blockIdx.x * blockDim.x + threadIdx.x;
    if (e < NE) slot[e] = atomicAdd(&counts[rows[e]], 1);
}

__global__ void scan_p1(const int* __restrict__ counts, int* __restrict__ partials) {
    __shared__ int red[256];
    int t = threadIdx.x;
    int i = blockIdx.x * 256 + t;
    red[t] = (i < NN) ? counts[i] : 0;
    __syncthreads();
    for (int off = 128; off > 0; off >>= 1) {
        if (t < off) red[t] += red[t + off];
        __syncthreads();
    }
    if (t == 0) partials[blockIdx.x] = red[0];
}

__global__ void scan_p2(int* __restrict__ partials) {
    __shared__ int sh[256];
    int t = threadIdx.x;
    int v = (t < NB_SCAN) ? partials[t] : 0;
    sh[t] = v;
    __syncthreads();
    for (int off = 1; off < 256; off <<= 1) {
        int u = (t >= off) ? sh[t - off] : 0;
        __syncthreads();
        sh[t] += u;
        __syncthreads();
    }
    if (t < NB_SCAN) partials[t] = sh[t] - v;
}

__global__ void scan_p3(const int* __restrict__ counts, const int* __restrict__ partials,
                        int* __restrict__ row_ptr) {
    __shared__ int sh[256];
    int t = threadIdx.x;
    int i = blockIdx.x * 256 + t;
    int v = (i < NN) ? counts[i] : 0;
    sh[t] = v;
    __syncthreads();
    for (int off = 1; off < 256; off <<= 1) {
        int u = (t >= off) ? sh[t - off] : 0;
        __syncthreads();
        sh[t] += u;
        __syncthreads();
    }
    int excl = sh[t] - v + partials[blockIdx.x];
    if (i < NN) row_ptr[i] = excl;
    if (i == NN - 1) row_ptr[NN] = excl + v;
}

// edge = col (low 16) | f16(val) (high 16)
__global__ void fill_edges(const int* __restrict__ rows, const int* __restrict__ cols,
                           const float* __restrict__ vals, const int* __restrict__ row_ptr,
                           const int* __restrict__ slot, uint32* __restrict__ edges) {
    int e = blockIdx.x * blockDim.x + threadIdx.x;
    if (e < NE) {
        int p = row_ptr[rows[e]] + slot[e];
        __half_raw hr = __half_raw(__float2half(vals[e]));
        edges[p] = (uint32)(cols[e] & 0xFFFF) | ((uint32)hr.x << 16);
    }
}

// -------- SpMM: Y = ca*A + cb*B + scale * sum val * Xb[col]  (Xb bf16) ------
// Y (f32) and/or Yb (bf16) may be null.
__global__ void spmm(const int* __restrict__ row_ptr, const uint32* __restrict__ edges,
                     const uint16* __restrict__ Xb, const float* __restrict__ A,
                     const float* __restrict__ B, float* __restrict__ Y,
                     uint16* __restrict__ Yb,
                     float scale, float ca, float cb, int n_nodes) {
    int tid  = threadIdx.x;
    int lane = tid & 31;
    int g    = tid >> 5;
    int r = blockIdx.x * 8 + g;
    if (r >= n_nodes) return;
    bool act = lane < 24;

    float4 acc = make_float4(0.f, 0.f, 0.f, 0.f);
    if (act) {
        float4 av = ((const float4*)(A + (size_t)r * D))[lane];
        float4 bv = ((const float4*)(B + (size_t)r * D))[lane];
        acc.x = ca * av.x + cb * bv.x;
        acc.y = ca * av.y + cb * bv.y;
        acc.z = ca * av.z + cb * bv.z;
        acc.w = ca * av.w + cb * bv.w;
    }

    int s = row_ptr[r];
    int e = row_ptr[r + 1];
    int i = s;
    for (; i + 3 < e; i += 4) {
        uint32 e0 = edges[i], e1 = edges[i+1], e2 = edges[i+2], e3 = edges[i+3];
        ushort4 x0, x1, x2, x3;
        x0.x=x0.y=x0.z=x0.w=0; x1=x0; x2=x0; x3=x0;
        if (act) {
            x0 = ((const ushort4*)(Xb + (size_t)(e0 & 0xFFFF) * D))[lane];
            x1 = ((const ushort4*)(Xb + (size_t)(e1 & 0xFFFF) * D))[lane];
            x2 = ((const ushort4*)(Xb + (size_t)(e2 & 0xFFFF) * D))[lane];
            x3 = ((const ushort4*)(Xb + (size_t)(e3 & 0xFFFF) * D))[lane];
        }
        __half_raw h0, h1, h2, h3;
        h0.x = (uint16)(e0 >> 16); h1.x = (uint16)(e1 >> 16);
        h2.x = (uint16)(e2 >> 16); h3.x = (uint16)(e3 >> 16);
        float v0 = scale * __half2float(__half(h0));
        float v1 = scale * __half2float(__half(h1));
        float v2 = scale * __half2float(__half(h2));
        float v3 = scale * __half2float(__half(h3));
        acc.x += v0*bf16_to_f32(x0.x) + v1*bf16_to_f32(x1.x) + v2*bf16_to_f32(x2.x) + v3*bf16_to_f32(x3.x);
        acc.y += v0*bf16_to_f32(x0.y) + v1*bf16_to_f32(x1.y) + v2*bf16_to_f32(x2.y) + v3*bf16_to_f32(x3.y);
        acc.z += v0*bf16_to_f32(x0.z) + v1*bf16_to_f32(x1.z) + v2*bf16_to_f32(x2.z) + v3*bf16_to_f32(x3.z);
        acc.w += v0*bf16_to_f32(x0.w) + v1*bf16_to_f32(x1.w) + v2*bf16_to_f32(x2.w) + v3*bf16_to_f32(x3.w);
    }
    for (; i < e; ++i) {
        uint32 e0 = edges[i];
        __half_raw h0; h0.x = (uint16)(e0 >> 16);
        float v0 = scale * __half2float(__half(h0));
        if (act) {
            ushort4 x0 = ((const ushort4*)(Xb + (size_t)(e0 & 0xFFFF) * D))[lane];
            acc.x += v0 * bf16_to_f32(x0.x);
            acc.y += v0 * bf16_to_f32(x0.y);
            acc.z += v0 * bf16_to_f32(x0.z);
            acc.w += v0 * bf16_to_f32(x0.w);
        }
    }
    if (act) {
        if (Y) ((float4*)(Y + (size_t)r * D))[lane] = acc;
        if (Yb) {
            ushort4 ob;
            ob.x = f32_to_bf16(acc.x); ob.y = f32_to_bf16(acc.y);
            ob.z = f32_to_bf16(acc.z); ob.w = f32_to_bf16(acc.w);
            ((ushort4*)(Yb + (size_t)r * D))[lane] = ob;
        }
    }
}

// ---- W -> B-operand fragment layout for mfma_f32_16x16x32_bf16 ----
// Wfrag[(nt*3+kc)*64 + lane][j] = bf16( W[kc*32 + (lane>>4)*8 + j][nt*16 + (lane&15)] )
__global__ void wfrag_prep(const float* __restrict__ W, uint16* __restrict__ Wfrag) {
    int bt = blockIdx.x;            // 0..17 = nt*3+kc
    int nt = bt / 3, kc = bt % 3;
    int lane = threadIdx.x;         // 0..63
    int col = nt * 16 + (lane & 15);
    int kbase = kc * 32 + (lane >> 4) * 8;
    uint16 tmp[8];
    #pragma unroll
    for (int j = 0; j < 8; ++j) tmp[j] = f32_to_bf16(W[(kbase + j) * D + col]);
    uint32* dst = (uint32*)(Wfrag + ((size_t)bt * 64 + lane) * 8);
    const uint32* src = (const uint32*)tmp;
    #pragma unroll
    for (int j = 0; j < 4; ++j) dst[j] = src[j];
}

// ---- out = Sb @ W + bias via MFMA; one wave per 16-row strip (grid-stride) --
__global__ void mfma_gemm(const uint16* __restrict__ Sb, const uint16* __restrict__ Wfrag,
                          const float* __restrict__ bias, float* __restrict__ out) {
    int tid   = threadIdx.x;
    int lane  = tid & 63;
    int wv    = blockIdx.x * (blockDim.x >> 6) + (tid >> 6);
    int nwv   = gridDim.x * (blockDim.x >> 6);
    int col   = lane & 15;
    int quad  = lane >> 4;

    v8s wf[6][3];
    #pragma unroll
    for (int nt = 0; nt < 6; ++nt)
        #pragma unroll
        for (int kc = 0; kc < 3; ++kc)
            wf[nt][kc] = ((const v8s*)Wfrag)[(nt * 3 + kc) * 64 + lane];

    float bi[6];
    #pragma unroll
    for (int nt = 0; nt < 6; ++nt) bi[nt] = bias[nt * 16 + col];

    for (int s = wv; s < NN / 16; s += nwv) {
        int r0 = s * 16;
        const uint16* arow = Sb + (size_t)(r0 + col) * D + quad * 8;
        v8s a0 = *((const v8s*)(arow));
        v8s a1 = *((const v8s*)(arow + 32));
        v8s a2 = *((const v8s*)(arow + 64));
        v4f acc[6];
        #pragma unroll
        for (int nt = 0; nt < 6; ++nt) {
            v4f c = {0.f, 0.f, 0.f, 0.f};
            c = __builtin_amdgcn_mfma_f32_16x16x32_bf16(a0, wf[nt][0], c, 0, 0, 0);
            c = __builtin_amdgcn_mfma_f32_16x16x32_bf16(a1, wf[nt][1], c, 0, 0, 0);
            c = __builtin_amdgcn_mfma_f32_16x16x32_bf16(a2, wf[nt][2], c, 0, 0, 0);
            acc[nt] = c;
        }
        #pragma unroll
        for (int nt = 0; nt < 6; ++nt) {
            float* o = out + (size_t)(r0 + quad * 4) * D + nt * 16 + col;
            o[0 * D] = acc[nt][0] + bi[nt];
            o[1 * D] = acc[nt][1] + bi[nt];
            o[2 * D] = acc[nt][2] + bi[nt];
            o[3 * D] = acc[nt][3] + bi[nt];
        }
    }
}

extern "C" void kernel_launch(void* const* d_in, const int* in_sizes, int n_in,
                              void* d_out, int out_size, void* d_ws, size_t ws_size,
                              hipStream_t stream) {
    const int*   rows = (const int*)d_in[0];
    const int*   cols = (const int*)d_in[1];
    const float* vals = (const float*)d_in[2];
    const float* H    = (const float*)d_in[3];
    const float* W    = (const float*)d_in[4];
    const float* bias = (const float*)d_in[5];
    float* out = (float*)d_out;

    char* ws = (char*)d_ws;
    float*  buf0     = (float*)ws;   ws += (size_t)NN * D * 4;   // slot -> T1
    float*  T2       = (float*)ws;   ws += (size_t)NN * D * 4;
    uint16* Hb       = (uint16*)ws;  ws += (size_t)NN * D * 2;
    uint16* T1b      = (uint16*)ws;  ws += (size_t)NN * D * 2;   // later Sb
    uint16* T2b      = (uint16*)ws;  ws += (size_t)NN * D * 2;
    uint32* edges    = (uint32*)ws;  ws += (size_t)NE * 4;
    uint16* Wfrag    = (uint16*)ws;  ws += (size_t)18 * 64 * 8 * 2;  // 18.4 KB
    int*    counts   = (int*)ws;     ws += (size_t)NN * 4;
    int*    row_ptr  = (int*)ws;     ws += (size_t)(NN + 1) * 4;
    int*    partials = (int*)ws;     ws += 256 * 4;
    int*    slot     = (int*)buf0;   // dead before spmm writes buf0
    float*  T1       = buf0;
    uint16* Sb       = T1b;          // T1b dead after pass 2 reads it

    const int nb  = (NN + 255) / 256;
    const int eb  = (NE + 255) / 256;
    const int n4  = NN * D / 4;
    const int cb4 = (n4 + 255) / 256;

    to_bf16<<<cb4, 256, 0, stream>>>((const float4*)H, (ushort4*)Hb, n4);
    wfrag_prep<<<18, 64, 0, stream>>>(W, Wfrag);

    zero_counts<<<nb, 256, 0, stream>>>(counts);
    hist_slots<<<eb, 256, 0, stream>>>(rows, counts, slot);
    scan_p1<<<NB_SCAN, 256, 0, stream>>>(counts, partials);
    scan_p2<<<1, 256, 0, stream>>>(partials);
    scan_p3<<<NB_SCAN, 256, 0, stream>>>(counts, partials, row_ptr);
    fill_edges<<<eb, 256, 0, stream>>>(rows, cols, vals, row_ptr, slot, edges);

    const int sb = (NN + 7) / 8;

    // T1 = 2*spmm(H) - H
    spmm<<<sb, 256, 0, stream>>>(row_ptr, edges, Hb, H, H, T1, T1b, 2.0f, -1.0f, 0.0f, NN);
    // T2 = 4*spmm(T1) - 2*T1 - H
    spmm<<<sb, 256, 0, stream>>>(row_ptr, edges, T1b, T1, H, T2, T2b, 4.0f, -2.0f, -1.0f, NN);
    // Sb = bf16( 4*spmm(T2) + H - T2 )   (= H+T1+T2+T3)
    spmm<<<sb, 256, 0, stream>>>(row_ptr, edges, T2b, H, T2, (float*)nullptr, Sb, 4.0f, 1.0f, -1.0f, NN);
    // out = Sb @ W + bias  (MFMA)
    mfma_gemm<<<391, 256, 0, stream>>>(Sb, Wfrag, bias, out);
}

// Round 6
// 240.718 us; speedup vs baseline: 12.9852x; 1.0738x over previous
//
#include <hip/hip_runtime.h>
#include <hip/hip_fp16.h>

#define NN 50000
#define NE 800000
#define D  96
#define NB_SCAN 196   // ceil(NN/256)
#define N4 (NN * D / 4)
#define CB4 ((N4 + 255) / 256)
#define WFRAG_BLKS 5  // ceil(18*64/256)

typedef unsigned int   uint32;
typedef unsigned short uint16;
typedef short v8s __attribute__((ext_vector_type(8)));   // 8 bf16 (4 VGPRs)
typedef float v4f __attribute__((ext_vector_type(4)));   // MFMA accumulator

__device__ inline uint16 f32_to_bf16(float f) {          // round-nearest-even
    uint32 u = __float_as_uint(f);
    u += 0x7FFF + ((u >> 16) & 1);
    return (uint16)(u >> 16);
}
__device__ inline float bf16_to_f32(uint16 h) {
    return __uint_as_float(((uint32)h) << 16);
}

// ---- fused prep: H->bf16 | zero counts | W->B-fragment layout ----
__global__ void prep(const float4* __restrict__ H, ushort4* __restrict__ Hb,
                     const float* __restrict__ W, uint16* __restrict__ Wfrag,
                     int* __restrict__ counts) {
    int b = blockIdx.x;
    int t = threadIdx.x;
    if (b < CB4) {
        int i = b * 256 + t;
        if (i < N4) {
            float4 v = H[i];
            ushort4 o;
            o.x = f32_to_bf16(v.x); o.y = f32_to_bf16(v.y);
            o.z = f32_to_bf16(v.z); o.w = f32_to_bf16(v.w);
            Hb[i] = o;
        }
    } else if (b < CB4 + NB_SCAN) {
        int i = (b - CB4) * 256 + t;
        if (i < NN) counts[i] = 0;
    } else {
        int idx = (b - CB4 - NB_SCAN) * 256 + t;   // 0..1151 = bt*64+lane
        if (idx < 18 * 64) {
            int bt = idx >> 6, lane = idx & 63;
            int nt = bt / 3, kc = bt % 3;
            int col = nt * 16 + (lane & 15);
            int kbase = kc * 32 + (lane >> 4) * 8;
            uint16 tmp[8];
            #pragma unroll
            for (int j = 0; j < 8; ++j) tmp[j] = f32_to_bf16(W[(kbase + j) * D + col]);
            uint32* dst = (uint32*)(Wfrag + ((size_t)bt * 64 + lane) * 8);
            const uint32* src = (const uint32*)tmp;
            #pragma unroll
            for (int j = 0; j < 4; ++j) dst[j] = src[j];
        }
    }
}

// ---------------- CSR build ----------------
__global__ void hist_slots(const int* __restrict__ rows, int* __restrict__ counts,
                           int* __restrict__ slot) {
    int e = blockIdx.x * blockDim.x + threadIdx.x;
    if (e < NE) slot[e] = atomicAdd(&counts[rows[e]], 1);
}

__global__ void scan_p1(const int* __restrict__ counts, int* __restrict__ partials) {
    __shared__ int red[256];
    int t = threadIdx.x;
    int i = blockIdx.x * 256 + t;
    red[t] = (i < NN) ? counts[i] : 0;
    __syncthreads();
    for (int off = 128; off > 0; off >>= 1) {
        if (t < off) red[t] += red[t + off];
        __syncthreads();
    }
    if (t == 0) partials[blockIdx.x] = red[0];
}

// fused: each block redundantly scans partials[NB_SCAN], then applies its
// local exclusive scan of counts -> row_ptr
__global__ void scan_p23(const int* __restrict__ counts, const int* __restrict__ partials,
                         int* __restrict__ row_ptr) {
    __shared__ int pp[256];
    __shared__ int sh[256];
    int t = threadIdx.x;
    // inclusive scan of partials
    pp[t] = (t < NB_SCAN) ? partials[t] : 0;
    __syncthreads();
    for (int off = 1; off < 256; off <<= 1) {
        int u = (t >= off) ? pp[t - off] : 0;
        __syncthreads();
        pp[t] += u;
        __syncthreads();
    }
    int blk_off = (blockIdx.x == 0) ? 0 : pp[blockIdx.x - 1];
    // local scan
    int i = blockIdx.x * 256 + t;
    int v = (i < NN) ? counts[i] : 0;
    sh[t] = v;
    __syncthreads();
    for (int off = 1; off < 256; off <<= 1) {
        int u = (t >= off) ? sh[t - off] : 0;
        __syncthreads();
        sh[t] += u;
        __syncthreads();
    }
    int excl = sh[t] - v + blk_off;
    if (i < NN) row_ptr[i] = excl;
    if (i == NN - 1) row_ptr[NN] = excl + v;
}

// edge = col (low 16) | f16(val) (high 16)
__global__ void fill_edges(const int* __restrict__ rows, const int* __restrict__ cols,
                           const float* __restrict__ vals, const int* __restrict__ row_ptr,
                           const int* __restrict__ slot, uint32* __restrict__ edges) {
    int e = blockIdx.x * blockDim.x + threadIdx.x;
    if (e < NE) {
        int p = row_ptr[rows[e]] + slot[e];
        __half_raw hr = __half_raw(__float2half(vals[e]));
        edges[p] = (uint32)(cols[e] & 0xFFFF) | ((uint32)hr.x << 16);
    }
}

// ---- SpMM (all bf16): Yb = bf16( ca*A + cb*B + scale * sum val * Xb[col] ) --
// 32 lanes per row; lanes 0..23 own 4 feats each (ushort4 = 8 B loads).
__global__ void spmm(const int* __restrict__ row_ptr, const uint32* __restrict__ edges,
                     const uint16* __restrict__ Xb, const uint16* __restrict__ A,
                     const uint16* __restrict__ B, uint16* __restrict__ Yb,
                     float scale, float ca, float cb, int n_nodes) {
    int tid  = threadIdx.x;
    int lane = tid & 31;
    int g    = tid >> 5;
    int r = blockIdx.x * 8 + g;
    if (r >= n_nodes) return;
    bool act = lane < 24;

    float4 acc = make_float4(0.f, 0.f, 0.f, 0.f);
    if (act) {
        ushort4 av = ((const ushort4*)(A + (size_t)r * D))[lane];
        ushort4 bv = ((const ushort4*)(B + (size_t)r * D))[lane];
        acc.x = ca * bf16_to_f32(av.x) + cb * bf16_to_f32(bv.x);
        acc.y = ca * bf16_to_f32(av.y) + cb * bf16_to_f32(bv.y);
        acc.z = ca * bf16_to_f32(av.z) + cb * bf16_to_f32(bv.z);
        acc.w = ca * bf16_to_f32(av.w) + cb * bf16_to_f32(bv.w);
    }

    int s = row_ptr[r];
    int e = row_ptr[r + 1];
    int i = s;
    for (; i + 3 < e; i += 4) {
        uint32 e0 = edges[i], e1 = edges[i+1], e2 = edges[i+2], e3 = edges[i+3];
        ushort4 x0, x1, x2, x3;
        x0.x=x0.y=x0.z=x0.w=0; x1=x0; x2=x0; x3=x0;
        if (act) {
            x0 = ((const ushort4*)(Xb + (size_t)(e0 & 0xFFFF) * D))[lane];
            x1 = ((const ushort4*)(Xb + (size_t)(e1 & 0xFFFF) * D))[lane];
            x2 = ((const ushort4*)(Xb + (size_t)(e2 & 0xFFFF) * D))[lane];
            x3 = ((const ushort4*)(Xb + (size_t)(e3 & 0xFFFF) * D))[lane];
        }
        __half_raw h0, h1, h2, h3;
        h0.x = (uint16)(e0 >> 16); h1.x = (uint16)(e1 >> 16);
        h2.x = (uint16)(e2 >> 16); h3.x = (uint16)(e3 >> 16);
        float v0 = scale * __half2float(__half(h0));
        float v1 = scale * __half2float(__half(h1));
        float v2 = scale * __half2float(__half(h2));
        float v3 = scale * __half2float(__half(h3));
        acc.x += v0*bf16_to_f32(x0.x) + v1*bf16_to_f32(x1.x) + v2*bf16_to_f32(x2.x) + v3*bf16_to_f32(x3.x);
        acc.y += v0*bf16_to_f32(x0.y) + v1*bf16_to_f32(x1.y) + v2*bf16_to_f32(x2.y) + v3*bf16_to_f32(x3.y);
        acc.z += v0*bf16_to_f32(x0.z) + v1*bf16_to_f32(x1.z) + v2*bf16_to_f32(x2.z) + v3*bf16_to_f32(x3.z);
        acc.w += v0*bf16_to_f32(x0.w) + v1*bf16_to_f32(x1.w) + v2*bf16_to_f32(x2.w) + v3*bf16_to_f32(x3.w);
    }
    for (; i < e; ++i) {
        uint32 e0 = edges[i];
        __half_raw h0; h0.x = (uint16)(e0 >> 16);
        float v0 = scale * __half2float(__half(h0));
        if (act) {
            ushort4 x0 = ((const ushort4*)(Xb + (size_t)(e0 & 0xFFFF) * D))[lane];
            acc.x += v0 * bf16_to_f32(x0.x);
            acc.y += v0 * bf16_to_f32(x0.y);
            acc.z += v0 * bf16_to_f32(x0.z);
            acc.w += v0 * bf16_to_f32(x0.w);
        }
    }
    if (act) {
        ushort4 ob;
        ob.x = f32_to_bf16(acc.x); ob.y = f32_to_bf16(acc.y);
        ob.z = f32_to_bf16(acc.z); ob.w = f32_to_bf16(acc.w);
        ((ushort4*)(Yb + (size_t)r * D))[lane] = ob;
    }
}

// ---- out = Sb @ W + bias via MFMA; one wave per 16-row strip (grid-stride) --
__global__ void mfma_gemm(const uint16* __restrict__ Sb, const uint16* __restrict__ Wfrag,
                          const float* __restrict__ bias, float* __restrict__ out) {
    int tid   = threadIdx.x;
    int lane  = tid & 63;
    int wv    = blockIdx.x * (blockDim.x >> 6) + (tid >> 6);
    int nwv   = gridDim.x * (blockDim.x >> 6);
    int col   = lane & 15;
    int quad  = lane >> 4;

    v8s wf[6][3];
    #pragma unroll
    for (int nt = 0; nt < 6; ++nt)
        #pragma unroll
        for (int kc = 0; kc < 3; ++kc)
            wf[nt][kc] = ((const v8s*)Wfrag)[(nt * 3 + kc) * 64 + lane];

    float bi[6];
    #pragma unroll
    for (int nt = 0; nt < 6; ++nt) bi[nt] = bias[nt * 16 + col];

    for (int s = wv; s < NN / 16; s += nwv) {
        int r0 = s * 16;
        const uint16* arow = Sb + (size_t)(r0 + col) * D + quad * 8;
        v8s a0 = *((const v8s*)(arow));
        v8s a1 = *((const v8s*)(arow + 32));
        v8s a2 = *((const v8s*)(arow + 64));
        v4f acc[6];
        #pragma unroll
        for (int nt = 0; nt < 6; ++nt) {
            v4f c = {0.f, 0.f, 0.f, 0.f};
            c = __builtin_amdgcn_mfma_f32_16x16x32_bf16(a0, wf[nt][0], c, 0, 0, 0);
            c = __builtin_amdgcn_mfma_f32_16x16x32_bf16(a1, wf[nt][1], c, 0, 0, 0);
            c = __builtin_amdgcn_mfma_f32_16x16x32_bf16(a2, wf[nt][2], c, 0, 0, 0);
            acc[nt] = c;
        }
        #pragma unroll
        for (int nt = 0; nt < 6; ++nt) {
            float* o = out + (size_t)(r0 + quad * 4) * D + nt * 16 + col;
            o[0 * D] = acc[nt][0] + bi[nt];
            o[1 * D] = acc[nt][1] + bi[nt];
            o[2 * D] = acc[nt][2] + bi[nt];
            o[3 * D] = acc[nt][3] + bi[nt];
        }
    }
}

extern "C" void kernel_launch(void* const* d_in, const int* in_sizes, int n_in,
                              void* d_out, int out_size, void* d_ws, size_t ws_size,
                              hipStream_t stream) {
    const int*   rows = (const int*)d_in[0];
    const int*   cols = (const int*)d_in[1];
    const float* vals = (const float*)d_in[2];
    const float* H    = (const float*)d_in[3];
    const float* W    = (const float*)d_in[4];
    const float* bias = (const float*)d_in[5];
    float* out = (float*)d_out;

    char* ws = (char*)d_ws;
    uint16* Hb       = (uint16*)ws;  ws += (size_t)NN * D * 2;   // 9.6 MB
    uint16* T1b      = (uint16*)ws;  ws += (size_t)NN * D * 2;   // later Sb
    uint16* T2b      = (uint16*)ws;  ws += (size_t)NN * D * 2;   // slot aliases here
    uint32* edges    = (uint32*)ws;  ws += (size_t)NE * 4;       // 3.2 MB
    uint16* Wfrag    = (uint16*)ws;  ws += (size_t)18 * 64 * 8 * 2;
    int*    counts   = (int*)ws;     ws += (size_t)NN * 4;
    int*    row_ptr  = (int*)ws;     ws += (size_t)(NN + 1) * 4;
    int*    partials = (int*)ws;     ws += 256 * 4;
    int*    slot     = (int*)T2b;    // dead before spmm pass 2 writes T2b
    uint16* Sb       = T1b;          // T1b dead after pass 2 reads it

    const int eb = (NE + 255) / 256;

    prep<<<CB4 + NB_SCAN + WFRAG_BLKS, 256, 0, stream>>>(
        (const float4*)H, (ushort4*)Hb, W, Wfrag, counts);
    hist_slots<<<eb, 256, 0, stream>>>(rows, counts, slot);
    scan_p1<<<NB_SCAN, 256, 0, stream>>>(counts, partials);
    scan_p23<<<NB_SCAN, 256, 0, stream>>>(counts, partials, row_ptr);
    fill_edges<<<eb, 256, 0, stream>>>(rows, cols, vals, row_ptr, slot, edges);

    const int sb = (NN + 7) / 8;

    // T1 = 2*spmm(H) - H
    spmm<<<sb, 256, 0, stream>>>(row_ptr, edges, Hb, Hb, Hb, T1b, 2.0f, -1.0f, 0.0f, NN);
    // T2 = 4*spmm(T1) - 2*T1 - H
    spmm<<<sb, 256, 0, stream>>>(row_ptr, edges, T1b, T1b, Hb, T2b, 4.0f, -2.0f, -1.0f, NN);
    // Sb = 4*spmm(T2) + H - T2   (= H+T1+T2+T3)
    spmm<<<sb, 256, 0, stream>>>(row_ptr, edges, T2b, Hb, T2b, Sb, 4.0f, 1.0f, -1.0f, NN);
    // out = Sb @ W + bias  (MFMA)
    mfma_gemm<<<391, 256, 0, stream>>>(Sb, Wfrag, bias, out);
}